// Round 1
// 2628.929 us; speedup vs baseline: 3.0913x; 3.0913x over previous
//
#include <hip/hip_runtime.h>
#include <hip/hip_bf16.h>
#include <math.h>

static constexpr int BB = 32;
static constexpr int TT = 256;
static constexpr int EE = 512;
static constexpr int HH = 512;
static constexpr int GG = 2048;  // 4H

static constexpr int WS = 20;  // wT_lds row stride (16 cols + 4 pad) -> sigma=5 (odd)
static constexpr int HS = 36;  // h_lds  row stride (32 b   + 4 pad) -> sigma=9 (odd)

using u16 = unsigned short;

__device__ __forceinline__ float bf2f(u16 u) {
    return __uint_as_float(((unsigned int)u) << 16);
}
__device__ __forceinline__ u16 f2bf(float f) {
    unsigned int u = __float_as_uint(f);
    unsigned int r = 0x7FFFu + ((u >> 16) & 1u);
    return (u16)((u + r) >> 16);
}
__device__ __forceinline__ float sigm(float x) {
    return 1.0f / (1.0f + expf(-x));
}

// ---- coherence-point (L3) accessors: sc0 sc1 = system-scope, bypass L1/L2.
// Using these for ALL cross-WG mutable data means NO buffer_wbl2 / buffer_inv
// is ever needed in the recurrent loop -> read-only xg/Whh stay L2-cached.
__device__ __forceinline__ float4 ld_b128_sc(const float4* p) {
    float4 v;
    asm volatile("global_load_dwordx4 %0, %1, off sc0 sc1" : "=v"(v) : "v"(p));
    return v;
}
__device__ __forceinline__ void st_b32_sc(float* p, float v) {
    asm volatile("global_store_dword %0, %1, off sc0 sc1" :: "v"(p), "v"(v) : "memory");
}

template<bool F32>
__device__ __forceinline__ float ldw(const void* p, size_t i) {
    if constexpr (F32) return ((const float*)p)[i];
    else               return bf2f(((const u16*)p)[i]);
}
template<bool F32>
__device__ __forceinline__ float4 ld4(const void* p, size_t i) {  // i % 4 == 0
    if constexpr (F32) {
        return *(const float4*)((const float*)p + i);
    } else {
        ushort4 v = *(const ushort4*)((const u16*)p + i);
        return make_float4(bf2f(v.x), bf2f(v.y), bf2f(v.z), bf2f(v.w));
    }
}

// ---------------- init: zero state, zero barrier, detect dtype ----------------
__global__ void init_state(const u16* __restrict__ bih_probe,
                           float* __restrict__ h_st, float* __restrict__ c_st,
                           int* __restrict__ bar, int* __restrict__ flag) {
    size_t i = (size_t)blockIdx.x * blockDim.x + threadIdx.x;
    size_t stride = (size_t)gridDim.x * blockDim.x;
    for (size_t j = i; j < (size_t)2*2*BB*HH; j += stride) h_st[j] = 0.0f;
    for (size_t j = i; j < (size_t)2*BB*HH;   j += stride) c_st[j] = 0.0f;
    for (size_t j = i; j < 1024;              j += stride) bar[j] = 0;
    if (blockIdx.x == 0 && threadIdx.x == 0) {
        int f = 0;
        for (int k = 0; k < 2048; ++k) {
            int e = (bih_probe[k] >> 7) & 0xFF;
            if (e >= 127) f = 1;
        }
        *flag = f;
    }
}

// ---------------- phase 1: xg = x @ Wih + bih + bhh ----------------
// Output layout: xg[d][t][nblk(128)][c0(16)][b(32)] fp32, c0 = g*4 + nl,
// col = g*512 + nblk*4 + nl. Per rec-WG per-step slice = contiguous 2 KB.
template<bool F32>
__device__ __forceinline__ void xg_body(
    const void* __restrict__ x, const void* __restrict__ Wih,
    const void* __restrict__ bih, const void* __restrict__ bhh,
    float* __restrict__ xgp, int d, int mt, int nt, float* b_lds)
{
    const int tid = threadIdx.x;
    const int tn = tid & 15;
    const int tm = tid >> 4;
    const int m0 = mt * 64;
    const int n0 = nt * 64;

    size_t a_off[4];
    #pragma unroll
    for (int i = 0; i < 4; ++i) {
        const int m = m0 + 4*tm + i;
        const int t = m >> 5, b = m & 31;
        const int t_src = d ? (TT - 1 - t) : t;
        a_off[i] = ((size_t)b * TT + t_src) * EE;
    }

    float acc[4][4];
    #pragma unroll
    for (int i = 0; i < 4; ++i)
        #pragma unroll
        for (int j = 0; j < 4; ++j) acc[i][j] = 0.0f;

    const int kr = tid >> 2;
    const int nc = (tid & 3) * 16;

    for (int k0 = 0; k0 < EE; k0 += 64) {
        __syncthreads();
        #pragma unroll 4
        for (int e = 0; e < 16; ++e)
            b_lds[kr*64 + nc + e] = ldw<F32>(Wih, (size_t)(k0 + kr)*GG + n0 + nc + e);
        __syncthreads();

        #pragma unroll 2
        for (int kk = 0; kk < 64; kk += 4) {
            float4 av[4];
            #pragma unroll
            for (int i = 0; i < 4; ++i) av[i] = ld4<F32>(x, a_off[i] + k0 + kk);
            #pragma unroll
            for (int j = 0; j < 4; ++j) {
                const float4 bv = *(const float4*)&b_lds[(kk + j)*64 + 4*tn];
                #pragma unroll
                for (int i = 0; i < 4; ++i) {
                    const float a = (j == 0) ? av[i].x : (j == 1) ? av[i].y
                                  : (j == 2) ? av[i].z : av[i].w;
                    acc[i][0] += a * bv.x; acc[i][1] += a * bv.y;
                    acc[i][2] += a * bv.z; acc[i][3] += a * bv.w;
                }
            }
        }
    }

    const int mbase = m0 + 4*tm;
    const int tt = mbase >> 5, bb = mbase & 31;   // 4 rows share t; b quad-aligned
    #pragma unroll
    for (int j = 0; j < 4; ++j) {
        const int col  = n0 + 4*tn + j;
        const float bs = ldw<F32>(bih, col) + ldw<F32>(bhh, col);
        const int g    = col >> 9;
        const int nblk = (col & 511) >> 2;
        const int nl   = col & 3;
        const size_t idx = (((size_t)d*TT + tt)*65536)
                         + (size_t)nblk*512 + (size_t)(g*4 + nl)*32 + bb;
        float4 v = make_float4(acc[0][j] + bs, acc[1][j] + bs,
                               acc[2][j] + bs, acc[3][j] + bs);
        *(float4*)&xgp[idx] = v;
    }
}

__global__ __launch_bounds__(256) void xg_gemm(
    const void* __restrict__ x,
    const void* __restrict__ WihF, const void* __restrict__ bihF, const void* __restrict__ bhhF,
    const void* __restrict__ WihB, const void* __restrict__ bihB, const void* __restrict__ bhhB,
    float* __restrict__ xgp, const int* __restrict__ flag)
{
    __shared__ float b_lds[64 * 64];
    const int bid = blockIdx.x;
    const int d  = bid >> 12;
    const int r  = bid & 4095;
    const int mt = r >> 5;
    const int nt = r & 31;
    const void* Wih = d ? WihB : WihF;
    const void* bih = d ? bihB : bihF;
    const void* bhh = d ? bhhB : bhhF;
    if (*flag) xg_body<true >(x, Wih, bih, bhh, xgp, d, mt, nt, b_lds);
    else       xg_body<false>(x, Wih, bih, bhh, xgp, d, mt, nt, b_lds);
}

// ---------------- phase 2: persistent recurrent kernel ----------------
// Grid: 256 WGs = dir(2) x nblk(128); 1 WG/CU (~114 KB LDS).
// h stored TRANSPOSED in ws: hT[d][parity][k(512)][b(32)] fp32.
//
// Cross-WG protocol (coherence-light; NO fences, NO wbl2/inv in the loop):
//  - producers write h with sc0 sc1 (write-through to L3, no L2 allocate)
//  - __syncthreads() drains each wave's vmcnt before s_barrier (hipcc emits
//    s_waitcnt vmcnt(0) pre-barrier; we add an explicit one for safety), so
//    all sc-stores are acked at the coherence point before tid0's counter add
//  - barrier counter: RELAXED agent-scope atomics (RMW executes at L3 with
//    sc1; relaxed ordering emits no cache-maintenance instructions)
//  - consumers load h with sc0 sc1 (bypass possibly-stale L1/L2)
//  => xg / Whh / out lines stay cached in L2 across the whole 256-step loop.
__device__ __forceinline__ void grid_bar_dir(int* __restrict__ bard, int wgl, int target) {
    asm volatile("s_waitcnt vmcnt(0)" ::: "memory");  // per-wave release: sc stores acked at L3
    __syncthreads();
    if (threadIdx.x == 0) {
        int v = __hip_atomic_fetch_add(&bard[32 + (wgl >> 4) * 32], 1,
                                       __ATOMIC_RELAXED, __HIP_MEMORY_SCOPE_AGENT);
        if ((v & 15) == 15)
            __hip_atomic_fetch_add(&bard[0], 1, __ATOMIC_RELAXED, __HIP_MEMORY_SCOPE_AGENT);
        while (__hip_atomic_load(&bard[0], __ATOMIC_RELAXED, __HIP_MEMORY_SCOPE_AGENT) < target)
            __builtin_amdgcn_s_sleep(1);
    }
    __syncthreads();
}

template<bool F32>
__device__ __forceinline__ void rec_body(
    const void* __restrict__ Whh,
    const float* __restrict__ xgp,   // [2][256][128][16][32] fp32 (biases folded)
    float* __restrict__ hT,          // [2 dir][2 parity][512 k][32 b] fp32
    int* __restrict__ bar,
    void* __restrict__ out, int d, int nblk, int wgl,
    float* __restrict__ wT_lds,      // [512][WS]
    float* __restrict__ h_lds,       // [512][HS]
    float* __restrict__ gbuf)        // [512]
{
    const int tid = threadIdx.x;
    const int cg = tid >> 6;          // wave id, 4 cols each
    const int bg = (tid >> 3) & 7;    // 4 batches each
    const int kg = tid & 7;           // k-split (lane bits 0..2), interleaved

    // ---- stage Whh transposed once: wT_lds[k*WS + ci] = Whh[k][col(ci)] ----
    {
        const int ci = tid & 15;
        const int cw = (ci >> 2)*512 + nblk*4 + (ci & 3);
        const int kb = (tid >> 4) * 32;
        #pragma unroll 4
        for (int k = kb; k < kb + 32; ++k)
            wT_lds[k*WS + ci] = ldw<F32>(Whh, (size_t)k*GG + cw);
    }

    int* bard = bar + d*512;          // d=0 -> bar[0..256], d=1 -> bar[512..768]
    float cr = 0.0f;                  // cell state (gate threads tid<128)
    const int gnl = tid >> 5;         // gate thread: nl (valid when tid<128)
    const int gb  = tid & 31;         // gate thread: b

    __syncthreads();

    for (int t = 0; t < TT; ++t) {
        const int parity = t & 1;
        const float4* hprev4 = (const float4*)(hT + (size_t)(d*2 + (parity ^ 1)) * 16384);
        float*        hnext  = hT + (size_t)(d*2 + parity) * 16384;

        // ---- prefetch xg (constant data; plain cached loads — stays in L2
        //      now that nothing invalidates it; overlap L2 latency with MAC) ----
        float xgv[4] = {0.f, 0.f, 0.f, 0.f};
        if (tid < 128) {
            const float* xgs = xgp + (((size_t)d*TT + t)*65536) + (size_t)nblk*512;
            #pragma unroll
            for (int g = 0; g < 4; ++g)
                xgv[g] = xgs[(g*4 + gnl)*32 + gb];
        }

        // ---- stage hT -> LDS via L3-coherent loads (bypass stale L1/L2) ----
        // issue all 16, single vmcnt(0), then LDS writes (memory ops cannot
        // cross the memory-clobber asm; sched_barrier for rule-18 paranoia)
        float4 hstg[16];
        #pragma unroll
        for (int i = 0; i < 16; ++i)
            hstg[i] = ld_b128_sc(hprev4 + i*256 + tid);
        asm volatile("s_waitcnt vmcnt(0)" ::: "memory");
        __builtin_amdgcn_sched_barrier(0);
        #pragma unroll
        for (int i = 0; i < 16; ++i) {
            const int idx = i*256 + tid;
            const int k  = idx >> 3;
            const int b4 = idx & 7;
            *(float4*)&h_lds[k*HS + b4*4] = hstg[i];
        }
        __syncthreads();

        // ---- MAC: acc[ci][bi], k = kk*8 + kg ----
        float acc[4][4];
        #pragma unroll
        for (int i = 0; i < 4; ++i)
            #pragma unroll
            for (int j = 0; j < 4; ++j) acc[i][j] = 0.0f;
        {
            const float* wp = wT_lds + kg*WS + cg*4;
            const float* hp = h_lds  + kg*HS + bg*4;
            #pragma unroll 8
            for (int kk = 0; kk < 64; ++kk) {
                const float4 wv = *(const float4*)(wp + kk*(8*WS));
                const float4 hv = *(const float4*)(hp + kk*(8*HS));
                acc[0][0] += wv.x*hv.x; acc[0][1] += wv.x*hv.y; acc[0][2] += wv.x*hv.z; acc[0][3] += wv.x*hv.w;
                acc[1][0] += wv.y*hv.x; acc[1][1] += wv.y*hv.y; acc[1][2] += wv.y*hv.z; acc[1][3] += wv.y*hv.w;
                acc[2][0] += wv.z*hv.x; acc[2][1] += wv.z*hv.y; acc[2][2] += wv.z*hv.z; acc[2][3] += wv.z*hv.w;
                acc[3][0] += wv.w*hv.x; acc[3][1] += wv.w*hv.y; acc[3][2] += wv.w*hv.z; acc[3][3] += wv.w*hv.w;
            }
        }
        // ---- reduce k-partials across kg (lane bits 0..2) ----
        #pragma unroll
        for (int i = 0; i < 4; ++i)
            #pragma unroll
            for (int j = 0; j < 4; ++j) {
                float v = acc[i][j];
                v += __shfl_xor(v, 1);
                v += __shfl_xor(v, 2);
                v += __shfl_xor(v, 4);
                acc[i][j] = v;
            }
        if (kg < 4) {
            const int ci = kg;
            *(float4*)&gbuf[(cg*4 + ci)*32 + bg*4] =
                make_float4(acc[ci][0], acc[ci][1], acc[ci][2], acc[ci][3]);
        }
        __syncthreads();

        // ---- gate combine: 128 threads, one (nl, b) each ----
        if (tid < 128) {
            const int nl = gnl;
            const int b  = gb;
            const float gi = gbuf[(0*4 + nl)*32 + b] + xgv[0];
            const float gf = gbuf[(1*4 + nl)*32 + b] + xgv[1];
            const float gc = gbuf[(2*4 + nl)*32 + b] + xgv[2];
            const float go = gbuf[(3*4 + nl)*32 + b] + xgv[3];
            const float cn = sigm(gf)*cr + sigm(gi)*tanhf(gc);
            cr = cn;
            const float hv = sigm(go)*tanhf(cn);
            const int ng = nblk*4 + nl;
            st_b32_sc(hnext + (size_t)ng*32 + b, hv);             // write-through to L3
            const size_t oi = ((size_t)b*TT + t)*(2*HH) + (size_t)d*HH + ng;
            if constexpr (F32) ((float*)out)[oi] = hv;
            else               ((u16*)out)[oi]   = f2bf(hv);
        }
        grid_bar_dir(bard, wgl, 8 * (t + 1));
    }
}

__global__ __launch_bounds__(256, 1) void lstm_rec(
    const void* __restrict__ WhhF, const void* __restrict__ WhhB,
    const float* __restrict__ xgp, float* __restrict__ hT,
    int* __restrict__ bar, const int* __restrict__ flag,
    void* __restrict__ out)
{
    __shared__ float wT_lds[512 * WS];   // 40 KB
    __shared__ float h_lds[512 * HS];    // 72 KB
    __shared__ float gbuf[512];          //  2 KB
    const int wg   = blockIdx.x;
    const int d    = wg >> 7;
    const int nblk = wg & 127;
    const void* Whh = d ? WhhB : WhhF;
    if (*flag) rec_body<true >(Whh, xgp, hT, bar, out, d, nblk, wg & 127, wT_lds, h_lds, gbuf);
    else       rec_body<false>(Whh, xgp, hT, bar, out, d, nblk, wg & 127, wT_lds, h_lds, gbuf);
}

// ---------------- fallback: proven round-3/4 per-step kernel ----------------
template<bool F32>
__device__ __forceinline__ void step_body(
    const void* __restrict__ x,
    const void* __restrict__ Wih, const void* __restrict__ bih,
    const void* __restrict__ Whh, const void* __restrict__ bhh,
    const float* __restrict__ h_prev, float* __restrict__ h_next,
    float* __restrict__ c_st, void* __restrict__ out,
    int d, int nblk, int t, int t_src, float* __restrict__ gbuf)
{
    const int tid = threadIdx.x;
    const int c0  = tid & 15;
    const int g   = c0 >> 2;
    const int nl  = c0 & 3;
    const int bq  = tid >> 4;
    const int col = g*512 + nblk*4 + nl;
    const int b0 = bq*2, b1 = b0 + 1;

    float p00=0.f,p01=0.f,p02=0.f,p03=0.f;
    float p10=0.f,p11=0.f,p12=0.f,p13=0.f;
    {
        const size_t xo0 = ((size_t)b0*TT + t_src) * EE;
        const size_t xo1 = ((size_t)b1*TT + t_src) * EE;
        #pragma unroll 4
        for (int k = 0; k < EE; k += 4) {
            const size_t wi = (size_t)k*GG + col;
            float w0 = ldw<F32>(Wih, wi);
            float w1 = ldw<F32>(Wih, wi +   (size_t)GG);
            float w2 = ldw<F32>(Wih, wi + 2*(size_t)GG);
            float w3 = ldw<F32>(Wih, wi + 3*(size_t)GG);
            float4 a0 = ld4<F32>(x, xo0 + k);
            float4 a1 = ld4<F32>(x, xo1 + k);
            p00 += w0*a0.x; p01 += w1*a0.y; p02 += w2*a0.z; p03 += w3*a0.w;
            p10 += w0*a1.x; p11 += w1*a1.y; p12 += w2*a1.z; p13 += w3*a1.w;
        }
    }
    {
        const float* hr0 = h_prev + (size_t)b0*HH;
        const float* hr1 = h_prev + (size_t)b1*HH;
        #pragma unroll 4
        for (int k = 0; k < HH; k += 4) {
            const size_t wi = (size_t)k*GG + col;
            float w0 = ldw<F32>(Whh, wi);
            float w1 = ldw<F32>(Whh, wi +   (size_t)GG);
            float w2 = ldw<F32>(Whh, wi + 2*(size_t)GG);
            float w3 = ldw<F32>(Whh, wi + 3*(size_t)GG);
            float4 v0 = *(const float4*)(hr0 + k);
            float4 v1 = *(const float4*)(hr1 + k);
            p00 += w0*v0.x; p01 += w1*v0.y; p02 += w2*v0.z; p03 += w3*v0.w;
            p10 += w0*v1.x; p11 += w1*v1.y; p12 += w2*v1.z; p13 += w3*v1.w;
        }
    }
    const float bias = ldw<F32>(bih, col) + ldw<F32>(bhh, col);
    gbuf[tid*2 + 0] = p00 + p01 + p02 + p03 + bias;
    gbuf[tid*2 + 1] = p10 + p11 + p12 + p13 + bias;
    __syncthreads();
    if (c0 < 4) {
        const int nlc = c0;
        const int ng  = nblk*4 + nlc;
        #pragma unroll
        for (int bi = 0; bi < 2; ++bi) {
            const int b = bq*2 + bi;
            const float gi = gbuf[(bq*16 + 0  + nlc)*2 + bi];
            const float gf = gbuf[(bq*16 + 4  + nlc)*2 + bi];
            const float gc = gbuf[(bq*16 + 8  + nlc)*2 + bi];
            const float go = gbuf[(bq*16 + 12 + nlc)*2 + bi];
            const size_t ci = (size_t)b*HH + ng;
            const float cp = c_st[ci];
            const float cn = sigm(gf)*cp + sigm(gi)*tanhf(gc);
            c_st[ci] = cn;
            const float hv = sigm(go)*tanhf(cn);
            h_next[ci] = hv;
            const size_t oi = ((size_t)b*TT + t)*(2*HH) + (size_t)d*HH + ng;
            if constexpr (F32) ((float*)out)[oi] = hv;
            else               ((u16*)out)[oi]   = f2bf(hv);
        }
    }
}

__global__ __launch_bounds__(256) void lstm_step(
    const void* __restrict__ x,
    const void* __restrict__ WihF, const void* __restrict__ bihF,
    const void* __restrict__ WhhF, const void* __restrict__ bhhF,
    const void* __restrict__ WihB, const void* __restrict__ bihB,
    const void* __restrict__ WhhB, const void* __restrict__ bhhB,
    float* __restrict__ h_buf, float* __restrict__ c_buf,
    const int* __restrict__ flag, void* __restrict__ out, int t)
{
    __shared__ float gbuf[512];
    const int bid  = blockIdx.x;
    const int d    = bid >> 7;
    const int nblk = bid & 127;
    const void* Wih = d ? WihB : WihF;
    const void* Whh = d ? WhhB : WhhF;
    const void* bih = d ? bihB : bihF;
    const void* bhh = d ? bhhB : bhhF;
    const int t_src  = d ? (TT - 1 - t) : t;
    const int parity = t & 1;
    const float* h_prev = h_buf + ((size_t)(d*2 + (parity ^ 1))) * BB * HH;
    float*       h_next = h_buf + ((size_t)(d*2 + parity)) * BB * HH;
    float*       c_st   = c_buf + (size_t)d * BB * HH;
    if (*flag) step_body<true >(x, Wih, bih, Whh, bhh, h_prev, h_next, c_st, out, d, nblk, t, t_src, gbuf);
    else       step_body<false>(x, Wih, bih, Whh, bhh, h_prev, h_next, c_st, out, d, nblk, t, t_src, gbuf);
}

// ---------------- host ----------------
extern "C" void kernel_launch(void* const* d_in, const int* in_sizes, int n_in,
                              void* d_out, int out_size, void* d_ws, size_t ws_size,
                              hipStream_t stream) {
    const void* x    = d_in[0];
    const void* WihF = d_in[1];
    const void* bihF = d_in[2];
    const void* WhhF = d_in[3];
    const void* bhhF = d_in[4];
    const void* WihB = d_in[5];
    const void* bihB = d_in[6];
    const void* WhhB = d_in[7];
    const void* bhhB = d_in[8];

    float* ws = (float*)d_ws;

    // layout (floats): xg[33554432] | h[65536] | c[32768] | bar[1024 ints] | flag
    const size_t off_xg = 0;
    const size_t off_h  = (size_t)2*TT*BB*GG;            // 33554432
    const size_t off_c  = off_h + (size_t)2*2*BB*HH;     // + 65536
    const size_t off_b  = off_c + (size_t)2*BB*HH;       // + 32768
    const size_t off_f  = off_b + 1024;
    const size_t need_bytes = (off_f + 16) * sizeof(float);

    if (ws_size >= need_bytes) {
        float* xgp  = ws + off_xg;
        float* hT   = ws + off_h;     // transposed: [2][2][512 k][32 b]
        float* cbuf = ws + off_c;     // unused by fast path (zeroed anyway)
        int*   bar  = (int*)(ws + off_b);
        int*   flag = (int*)(ws + off_f);

        init_state<<<64, 256, 0, stream>>>((const u16*)bihF, hT, cbuf, bar, flag);
        xg_gemm<<<8192, 256, 0, stream>>>(x, WihF, bihF, bhhF, WihB, bihB, bhhB, xgp, flag);
        lstm_rec<<<256, 256, 0, stream>>>(WhhF, WhhB, xgp, hT, bar, flag, d_out);
    } else {
        float* h_buf = ws;
        float* c_buf = ws + (size_t)2*2*BB*HH;
        int*   bar   = (int*)(c_buf + (size_t)2*BB*HH);
        int*   flag  = (int*)(bar + 1024);
        init_state<<<64, 256, 0, stream>>>((const u16*)bihF, h_buf, c_buf, bar, flag);
        for (int t = 0; t < TT; ++t) {
            lstm_step<<<256, 256, 0, stream>>>(x, WihF, bihF, WhhF, bhhF,
                                               WihB, bihB, WhhB, bhhB,
                                               h_buf, c_buf, flag, d_out, t);
        }
    }
}